// Round 6
// baseline (552.250 us; speedup 1.0000x reference)
//
#include <hip/hip_runtime.h>
#include <cstdint>
#include <cstddef>

// Problem constants (fixed by reference setup_inputs)
#define BATCH 8
#define CH    128
#define NPTS  65536
#define NOBJ  64
#define SEGEL (CH * NOBJ)      // 8192 partial elements per block

// ---- transposed main path geometry ----
#define TPB3  256              // 4 waves: 2 channel-halves x 2 point-halves
#define PPB3  1024             // points per block
#define NCH3  (NPTS / PPB3)    // 64 chunks per batch -> 512 blocks
#define HPTS  (PPB3 / 2)       // 512 points per wave

// ---------------------------------------------------------------------------
// seg_max_t: lane = channel. All 64 lanes of a wave process the SAME point,
// so the segment is wave-uniform (scalar) and the accumulator row
// acc[wave][seg][lane] is hit conflict-free with plain read/fmax/write —
// NO atomics, 2 DS instrs per point per wave = 2 DS instrs per 64 values
// (R4/R5 spent >=1 DS lane-op per value; the DS pipe was the measured
// invariant bottleneck at ~105us). Same-seg duplicates inside a 4-point
// group are pre-combined in VALU (scalar compares) to keep RMW race-free.
// ---------------------------------------------------------------------------
__global__ __launch_bounds__(TPB3) void seg_max_t(
        const float* __restrict__ pf,     // (B, C, N)
        const int*   __restrict__ bidx,   // (B, N)
        float*       __restrict__ ws)     // (B*NCH3, SEGEL) raw f32 partials
{
    __shared__ float acc[4][NOBJ][64];    // 64 KiB: [wave][seg][chan-lane]

    const int tid = threadIdx.x;
    const int w   = tid >> 6;             // wave 0..3
    const int l   = tid & 63;             // lane = channel-local
    const int h   = w & 1;                // channel half (0: c<64, 1: c>=64)
    const int q   = w >> 1;               // point half

    const int b     = blockIdx.x / NCH3;
    const int chunk = blockIdx.x % NCH3;
    const int n0    = chunk * PPB3;

    float (*aw)[64] = acc[w];
    #pragma unroll
    for (int s = 0; s < NOBJ; ++s) aw[s][l] = -INFINITY;   // conflict-free

    const int np = n0 + q * HPTS;
    const float* prow = pf + ((size_t)b * CH + (size_t)(h * 64 + l)) * NPTS + np;
    const int*   srow = bidx + (size_t)b * NPTS + np;

    float4 v = *(const float4*)prow;      // prefetch group 0
    for (int p0 = 0; p0 < HPTS; p0 += 4) {
        const float4 cur = v;
        if (p0 + 4 < HPTS) v = *(const float4*)(prow + p0 + 4);

        // Wave-uniform segment ids (one broadcast load + readfirstlane).
        const int4 sv = *(const int4*)(srow + p0);
        const int s0 = __builtin_amdgcn_readfirstlane(sv.x);
        const int s1 = __builtin_amdgcn_readfirstlane(sv.y);
        const int s2 = __builtin_amdgcn_readfirstlane(sv.z);
        const int s3 = __builtin_amdgcn_readfirstlane(sv.w);

        // Pre-combine duplicate segs into the LAST occurrence (scalar cmps).
        float x0 = cur.x, x1 = cur.y, x2 = cur.z, x3 = cur.w;
        bool k0 = false, k1 = false, k2 = false;
        if (s1 == s0)      { x1 = fmaxf(x1, x0); k0 = true; }
        if (s2 == s1)      { x2 = fmaxf(x2, x1); k1 = true; }
        else if (s2 == s0) { x2 = fmaxf(x2, x0); k0 = true; }
        if (s3 == s2)      { x3 = fmaxf(x3, x2); k2 = true; }
        else if (s3 == s1) { x3 = fmaxf(x3, x1); k1 = true; }
        else if (s3 == s0) { x3 = fmaxf(x3, x0); k0 = true; }

        // Reads first (pipelined), then writes — live segs are distinct.
        const float a0 = aw[s0][l];
        const float a1 = aw[s1][l];
        const float a2 = aw[s2][l];
        const float a3 = aw[s3][l];
        if (!k0) aw[s0][l] = fmaxf(a0, x0);
        if (!k1) aw[s1][l] = fmaxf(a1, x1);
        if (!k2) aw[s2][l] = fmaxf(a2, x2);
        aw[s3][l] = fmaxf(a3, x3);
    }
    __syncthreads();

    // Merge point-halves, dump partials: ws[block][seg*128 + c] (== output
    // element order within a batch). Conflict-free LDS reads, coalesced store.
    float* wsb = ws + (size_t)blockIdx.x * SEGEL;
    for (int e = tid; e < SEGEL; e += TPB3) {
        const int c   = e & 127;
        const int seg = e >> 7;
        const int hh  = c >> 6;
        const int cl  = c & 63;
        wsb[e] = fmaxf(acc[hh][seg][cl], acc[hh + 2][seg][cl]);
    }
}

// Max over per-chunk partials + empty-segment guard. ws element order inside
// a batch equals output order, so out index == g.
template <int NCHUNK>
__global__ __launch_bounds__(256) void reduce_ws_f(
        const float* __restrict__ ws, float* __restrict__ out)
{
    const int g = blockIdx.x * 256 + threadIdx.x;   // 0 .. B*SEGEL-1
    const float* p = ws + (size_t)(g >> 13) * NCHUNK * SEGEL + (g & (SEGEL - 1));
    float m = -INFINITY;
    #pragma unroll
    for (int k = 0; k < NCHUNK; ++k) m = fmaxf(m, p[(size_t)k * SEGEL]);
    if (!isfinite(m)) m = 0.0f;
    out[g] = m;
}

// ---------------------------------------------------------------------------
// Fallback path (ws too small): LDS-atomic accumulate + global-atomic merge.
// ---------------------------------------------------------------------------
__device__ __forceinline__ uint32_t enc_f32(float f) {
    uint32_t x = __float_as_uint(f);
    return x ^ ((uint32_t)((int32_t)x >> 31) | 0x80000000u);
}
__device__ __forceinline__ float dec_f32(uint32_t u) {
    uint32_t x = u ^ ((uint32_t)((int32_t)(~u) >> 31) | 0x80000000u);
    return __uint_as_float(x);
}

__global__ __launch_bounds__(256) void init_out_kernel(uint32_t* __restrict__ out, int n) {
    int i = blockIdx.x * blockDim.x + threadIdx.x;
    if (i < n) out[i] = 0u;
}

__global__ __launch_bounds__(256) void seg_max_atomic(
        const float* __restrict__ pf, const int* __restrict__ bidx,
        uint32_t* __restrict__ out)
{
    constexpr int PPB = 1024;
    __shared__ uint32_t acc[SEGEL];
    const int tid   = threadIdx.x;
    const int b     = blockIdx.x / (NPTS / PPB);
    const int chunk = blockIdx.x % (NPTS / PPB);
    const int n0    = chunk * PPB;
    for (int i = tid; i < SEGEL; i += 256) acc[i] = 0u;
    __syncthreads();
    const int4 sv = *(const int4*)(bidx + (size_t)b * NPTS + n0 + tid * 4);
    const float* p = pf + (size_t)b * CH * NPTS + n0 + tid * 4;
    uint32_t* row = acc;
    #pragma unroll 4
    for (int c = 0; c < CH; ++c, p += NPTS, row += NOBJ) {
        const float4 v = *(const float4*)p;
        atomicMax(&row[sv.x], enc_f32(v.x));
        atomicMax(&row[sv.y], enc_f32(v.y));
        atomicMax(&row[sv.z], enc_f32(v.z));
        atomicMax(&row[sv.w], enc_f32(v.w));
    }
    __syncthreads();
    for (int e = tid; e < SEGEL; e += 256) {
        const int seg = e & (NOBJ - 1);
        const int c   = e >> 6;
        const uint32_t v = acc[c * NOBJ + seg];
        if (v) atomicMax(&out[(size_t)(b * NOBJ + seg) * CH + c], v);
    }
}

__global__ __launch_bounds__(256) void finalize_kernel(uint32_t* __restrict__ out, int n) {
    int i = blockIdx.x * blockDim.x + threadIdx.x;
    if (i >= n) return;
    const uint32_t u = out[i];
    float f = 0.0f;
    if (u) { f = dec_f32(u); if (!isfinite(f)) f = 0.0f; }
    ((float*)out)[i] = f;
}

extern "C" void kernel_launch(void* const* d_in, const int* in_sizes, int n_in,
                              void* d_out, int out_size, void* d_ws, size_t ws_size,
                              hipStream_t stream) {
    const float* pf   = (const float*)d_in[0];
    const int*   bidx = (const int*)d_in[1];

    const size_t need = (size_t)BATCH * NCH3 * SEGEL * sizeof(float);   // 16 MiB

    if (ws_size >= need) {
        float* ws = (float*)d_ws;
        seg_max_t<<<BATCH * NCH3, TPB3, 0, stream>>>(pf, bidx, ws);
        reduce_ws_f<NCH3><<<(BATCH * SEGEL) / 256, 256, 0, stream>>>(ws, (float*)d_out);
    } else {
        uint32_t* out = (uint32_t*)d_out;
        init_out_kernel<<<(out_size + 255) / 256, 256, 0, stream>>>(out, out_size);
        seg_max_atomic<<<BATCH * (NPTS / 1024), 256, 0, stream>>>(pf, bidx, out);
        finalize_kernel<<<(out_size + 255) / 256, 256, 0, stream>>>(out, out_size);
    }
}